// Round 1
// baseline (366.461 us; speedup 1.0000x reference)
//
#include <hip/hip_runtime.h>
#include <hip/hip_bf16.h>
#include <math.h>

#define NN 4096
#define DD 127
#define HH 128
#define OUTD 3
#define NTYPES 6
#define SIM_THRESH 0.9f
#define BN_EPS 1e-5f

// ---------------------------------------------------------------------------
// Kernel A: build x = concat(x_now[:, :1], x_now) (N x 128), normalized
// feature fn[i] = normalize([x0,x0,x1,x2]), and per-type counts.
// ---------------------------------------------------------------------------
__global__ __launch_bounds__(HH) void build_x_fn(
    const float* __restrict__ x_now, const int* __restrict__ sat,
    float* __restrict__ x, float4* __restrict__ fn, int* __restrict__ cnt)
{
    int i = blockIdx.x;
    int k = threadIdx.x;
    const float* row = x_now + (size_t)i * DD;
    float v = (k == 0) ? row[0] : row[k - 1];
    x[(size_t)i * HH + k] = v;
    if (k == 0) {
        float f0 = row[0], f2 = row[1], f3 = row[2];
        float nrm = sqrtf(2.f * f0 * f0 + f2 * f2 + f3 * f3);
        nrm = fmaxf(nrm, 1e-12f);
        float inv = 1.f / nrm;
        fn[i] = make_float4(f0 * inv, f0 * inv, f2 * inv, f3 * inv);
        int t = sat[i]; t = min(max(t, 0), NTYPES - 1);
        atomicAdd(&cnt[t], 1);
    }
}

// ---------------------------------------------------------------------------
// Kernel B: cross-type cosine adjacency bitmask + degree.
// Bit layout: word w (0..127) of row i, bit b (0..31) <-> j = b*128 + w.
// (so at inner iteration b, threads w=0..127 load fn[b*128+w] coalesced)
// deg[i] = max(cnt[type(i)]-1 + popcount(row i), 1)
// ---------------------------------------------------------------------------
__global__ __launch_bounds__(HH) void build_mask(
    const float4* __restrict__ fn, const int* __restrict__ sat,
    const int* __restrict__ cnt, unsigned* __restrict__ mask,
    float* __restrict__ deg)
{
    int i = blockIdx.x;
    int w = threadIdx.x;  // 0..127
    float4 fi = fn[i];
    int ti = sat[i]; ti = min(max(ti, 0), NTYPES - 1);
    unsigned word = 0;
    for (int b = 0; b < 32; ++b) {
        int j = b * 128 + w;
        float4 fj = fn[j];
        float dot = fi.x * fj.x + fi.y * fj.y + fi.z * fj.z + fi.w * fj.w;
        int tj = sat[j];
        if (tj != ti && dot > SIM_THRESH) word |= (1u << b);
    }
    mask[(size_t)i * 128 + w] = word;

    __shared__ int sred[HH];
    sred[w] = __popc(word);
    __syncthreads();
    for (int s = 64; s > 0; s >>= 1) {
        if (w < s) sred[w] += sred[w + s];
        __syncthreads();
    }
    if (w == 0) {
        float d = (float)(cnt[ti] - 1 + sred[0]);
        deg[i] = fmaxf(d, 1.0f);
    }
}

// ---------------------------------------------------------------------------
// Kernel C: per-type column sums S[t][k] = sum_{i: type(i)=t} h[i][k]
// 32 blocks x 128 threads; block handles 128 rows; thread owns column k.
// ---------------------------------------------------------------------------
__global__ __launch_bounds__(HH) void type_sums(
    const float* __restrict__ h, const int* __restrict__ sat,
    float* __restrict__ S)
{
    int k = threadIdx.x;
    int base = blockIdx.x * 128;
    __shared__ float ls[NTYPES][HH];
    for (int t = 0; t < NTYPES; ++t) ls[t][k] = 0.f;
    for (int r = 0; r < 128; ++r) {
        int i = base + r;
        int t = sat[i]; t = min(max(t, 0), NTYPES - 1);
        ls[t][k] += h[(size_t)i * HH + k];
    }
    for (int t = 0; t < NTYPES; ++t) atomicAdd(&S[t * HH + k], ls[t][k]);
}

// ---------------------------------------------------------------------------
// Kernel D: one GCN layer for one row i per block.
//  m[k] = (S[t_i][k] - h[i][k] + sum_{bitmask j} h[j][k]) / deg[i]
//  hout[i][o] = relu( sum_k m[k]*Wl[o][k] + h[i][k]*Wr[o][k] + bl[o] )
// ---------------------------------------------------------------------------
__global__ __launch_bounds__(HH) void layer_kernel(
    const float* __restrict__ h, const unsigned* __restrict__ mask,
    const float* __restrict__ deg, const float* __restrict__ S,
    const int* __restrict__ sat,
    const float* __restrict__ Wl, const float* __restrict__ bl,
    const float* __restrict__ Wr, float* __restrict__ hout)
{
    int i = blockIdx.x;
    int k = threadIdx.x;
    __shared__ unsigned mrow[128];
    __shared__ __align__(16) float ms[HH];
    __shared__ __align__(16) float hs[HH];

    mrow[k] = mask[(size_t)i * 128 + k];
    float hv = h[(size_t)i * HH + k];
    hs[k] = hv;
    __syncthreads();

    float e = 0.f;
    for (int w = 0; w < 128; ++w) {
        unsigned word = mrow[w];  // uniform across threads
        while (word) {
            int b = __ffs(word) - 1;
            word &= word - 1;
            int j = b * 128 + w;
            e += h[(size_t)j * HH + k];   // coalesced across k
        }
    }
    int ti = sat[i]; ti = min(max(ti, 0), NTYPES - 1);
    float rdeg = 1.f / deg[i];
    ms[k] = (S[ti * HH + k] - hv + e) * rdeg;
    __syncthreads();

    // thread k now acts as output index o
    const float4* Wl4 = (const float4*)Wl + k * 32;
    const float4* Wr4 = (const float4*)Wr + k * 32;
    const float4* ms4 = (const float4*)ms;
    const float4* hs4 = (const float4*)hs;
    float acc = bl[k];
    for (int q = 0; q < 32; ++q) {
        float4 a = ms4[q], wa = Wl4[q];
        float4 bb = hs4[q], wb = Wr4[q];
        acc += a.x * wa.x + a.y * wa.y + a.z * wa.z + a.w * wa.w;
        acc += bb.x * wb.x + bb.y * wb.y + bb.z * wb.z + bb.w * wb.w;
    }
    hout[(size_t)i * HH + k] = fmaxf(acc, 0.f);
}

// ---------------------------------------------------------------------------
// Kernel E: batchnorm stats (sum, sumsq per column)
// ---------------------------------------------------------------------------
__global__ __launch_bounds__(HH) void bn_stats(
    const float* __restrict__ h, float* __restrict__ musum,
    float* __restrict__ varsum)
{
    int k = threadIdx.x;
    int base = blockIdx.x * 128;
    float s = 0.f, s2 = 0.f;
    for (int r = 0; r < 128; ++r) {
        float v = h[(size_t)(base + r) * HH + k];
        s += v; s2 += v * v;
    }
    atomicAdd(&musum[k], s);
    atomicAdd(&varsum[k], s2);
}

// ---------------------------------------------------------------------------
// Kernel F: batchnorm apply + output head
// ---------------------------------------------------------------------------
__global__ __launch_bounds__(HH) void finalize(
    const float* __restrict__ h, const float* __restrict__ musum,
    const float* __restrict__ varsum, const float* __restrict__ gamma,
    const float* __restrict__ beta, const float* __restrict__ Wo,
    const float* __restrict__ bo, float* __restrict__ out_h,
    float* __restrict__ out_o)
{
    int i = blockIdx.x;
    int k = threadIdx.x;
    float mu = musum[k] * (1.f / NN);
    float var = varsum[k] * (1.f / NN) - mu * mu;
    float inv = 1.f / sqrtf(var + BN_EPS);
    float hv = h[(size_t)i * HH + k];
    float hb = (hv - mu) * inv * gamma[k] + beta[k];
    out_h[(size_t)i * HH + k] = hb;

    __shared__ float red[HH];
    for (int o = 0; o < OUTD; ++o) {
        red[k] = hb * Wo[o * HH + k];
        __syncthreads();
        for (int s = 64; s > 0; s >>= 1) {
            if (k < s) red[k] += red[k + s];
            __syncthreads();
        }
        if (k == 0) out_o[(size_t)i * OUTD + o] = red[0] + bo[o];
        __syncthreads();
    }
}

// ---------------------------------------------------------------------------
extern "C" void kernel_launch(void* const* d_in, const int* in_sizes, int n_in,
                              void* d_out, int out_size, void* d_ws, size_t ws_size,
                              hipStream_t stream)
{
    (void)in_sizes; (void)n_in; (void)out_size; (void)ws_size;
    const float* x_now = (const float*)d_in[0];
    const int*   sat   = (const int*)d_in[1];
    const float* Wl    = (const float*)d_in[2];
    const float* bl    = (const float*)d_in[3];
    const float* Wr    = (const float*)d_in[4];
    const float* gamma = (const float*)d_in[5];
    const float* beta  = (const float*)d_in[6];
    const float* Wo    = (const float*)d_in[7];
    const float* bo    = (const float*)d_in[8];

    float* ws = (float*)d_ws;
    float* x0 = ws;                          // 524288 floats
    float* h1 = x0 + (size_t)NN * HH;        // 524288
    float* h2 = h1 + (size_t)NN * HH;        // 524288
    float4* fn = (float4*)(h2 + (size_t)NN * HH);      // 4096 float4
    unsigned* mask = (unsigned*)((float*)fn + 4 * NN); // 524288 words
    float* deg = (float*)(mask + (size_t)NN * 128);    // 4096
    int* cnt = (int*)(deg + NN);             // 8 ints
    float* S0 = (float*)(cnt + 8);           // 768
    float* S1 = S0 + NTYPES * HH;            // 768
    float* musum = S1 + NTYPES * HH;         // 128
    float* varsum = musum + HH;              // 128

    size_t zero_bytes = (8 + 2 * NTYPES * HH + 2 * HH) * sizeof(float);
    hipMemsetAsync(cnt, 0, zero_bytes, stream);

    build_x_fn<<<NN, HH, 0, stream>>>(x_now, sat, x0, fn, cnt);
    build_mask<<<NN, HH, 0, stream>>>(fn, sat, cnt, mask, deg);

    type_sums<<<32, HH, 0, stream>>>(x0, sat, S0);
    layer_kernel<<<NN, HH, 0, stream>>>(x0, mask, deg, S0, sat,
                                        Wl, bl, Wr, h1);
    type_sums<<<32, HH, 0, stream>>>(h1, sat, S1);
    layer_kernel<<<NN, HH, 0, stream>>>(h1, mask, deg, S1, sat,
                                        Wl + 16384, bl + HH, Wr + 16384, h2);

    bn_stats<<<32, HH, 0, stream>>>(h2, musum, varsum);
    finalize<<<NN, HH, 0, stream>>>(h2, musum, varsum, gamma, beta, Wo, bo,
                                    (float*)d_out, (float*)d_out + (size_t)NN * HH);
}

// Round 2
// 242.445 us; speedup vs baseline: 1.5115x; 1.5115x over previous
//
#include <hip/hip_runtime.h>
#include <hip/hip_bf16.h>
#include <math.h>

#define NN 4096
#define DD 127
#define HH 128
#define OUTD 3
#define NTYPES 6
#define SIM_THRESH 0.9f
#define BN_EPS 1e-5f
#define RPB 4   // rows per block in layer_kernel: amortizes W loads 4x

// ---------------------------------------------------------------------------
// Kernel A: build x = concat(x_now[:, :1], x_now) (N x 128), normalized
// feature fn[i] = normalize([x0,x0,x1,x2]), and per-type counts.
// ---------------------------------------------------------------------------
__global__ __launch_bounds__(HH) void build_x_fn(
    const float* __restrict__ x_now, const int* __restrict__ sat,
    float* __restrict__ x, float4* __restrict__ fn, int* __restrict__ cnt)
{
    int i = blockIdx.x;
    int k = threadIdx.x;
    const float* row = x_now + (size_t)i * DD;
    float v = (k == 0) ? row[0] : row[k - 1];
    x[(size_t)i * HH + k] = v;
    if (k == 0) {
        float f0 = row[0], f2 = row[1], f3 = row[2];
        float nrm = sqrtf(2.f * f0 * f0 + f2 * f2 + f3 * f3);
        nrm = fmaxf(nrm, 1e-12f);
        float inv = 1.f / nrm;
        fn[i] = make_float4(f0 * inv, f0 * inv, f2 * inv, f3 * inv);
        int t = sat[i]; t = min(max(t, 0), NTYPES - 1);
        atomicAdd(&cnt[t], 1);
    }
}

// ---------------------------------------------------------------------------
// Kernel B: cross-type cosine adjacency bitmask + degree.
// Bit layout: word w (0..127) of row i, bit b (0..31) <-> j = b*128 + w.
// ---------------------------------------------------------------------------
__global__ __launch_bounds__(HH) void build_mask(
    const float4* __restrict__ fn, const int* __restrict__ sat,
    const int* __restrict__ cnt, unsigned* __restrict__ mask,
    float* __restrict__ deg)
{
    int i = blockIdx.x;
    int w = threadIdx.x;  // 0..127
    float4 fi = fn[i];
    int ti = sat[i]; ti = min(max(ti, 0), NTYPES - 1);
    unsigned word = 0;
    for (int b = 0; b < 32; ++b) {
        int j = b * 128 + w;
        float4 fj = fn[j];
        float dot = fi.x * fj.x + fi.y * fj.y + fi.z * fj.z + fi.w * fj.w;
        int tj = sat[j];
        if (tj != ti && dot > SIM_THRESH) word |= (1u << b);
    }
    mask[(size_t)i * 128 + w] = word;

    int pc = __popc(word);
    int lane = w & 63, wv = w >> 6;
    for (int s = 32; s; s >>= 1) pc += __shfl_down(pc, s);
    __shared__ int wt[2];
    if (lane == 0) wt[wv] = pc;
    __syncthreads();
    if (w == 0) {
        float d = (float)(cnt[ti] - 1 + wt[0] + wt[1]);
        deg[i] = fmaxf(d, 1.0f);
    }
}

// ---------------------------------------------------------------------------
// Kernel C: per-type column sums S[t][k] = sum_{i: type(i)=t} h[i][k]
// ---------------------------------------------------------------------------
__global__ __launch_bounds__(HH) void type_sums(
    const float* __restrict__ h, const int* __restrict__ sat,
    float* __restrict__ S)
{
    int k = threadIdx.x;
    int base = blockIdx.x * 128;
    __shared__ float ls[NTYPES][HH];
    for (int t = 0; t < NTYPES; ++t) ls[t][k] = 0.f;
    for (int r = 0; r < 128; ++r) {
        int i = base + r;
        int t = sat[i]; t = min(max(t, 0), NTYPES - 1);
        ls[t][k] += h[(size_t)i * HH + k];
    }
    for (int t = 0; t < NTYPES; ++t) atomicAdd(&S[t * HH + k], ls[t][k]);
}

// ---------------------------------------------------------------------------
// Kernel D v2: RPB rows per block.
// Per row: decode bitmask -> LDS CSR list (wave shfl scan); gather as
// 4 neighbors x 32 float4 chunks with 4 independent accumulators (4
// dwordx4 loads in flight per wave); LDS reduce across neighbor slots.
// Then one matmul phase: W float4 loaded once per block, reused across RPB
// rows via LDS broadcast of ms/hs.
// ---------------------------------------------------------------------------
__global__ __launch_bounds__(HH) void layer_kernel(
    const float* __restrict__ h, const unsigned* __restrict__ mask,
    const float* __restrict__ deg, const float* __restrict__ S,
    const int* __restrict__ sat,
    const float* __restrict__ Wl, const float* __restrict__ bl,
    const float* __restrict__ Wr, float* __restrict__ hout)
{
    int t = threadIdx.x;
    int i0 = blockIdx.x * RPB;
    __shared__ unsigned short list[NN];                 // 8 KB CSR scratch
    __shared__ int wtot[2];
    __shared__ __align__(16) float hs[RPB][HH];
    __shared__ __align__(16) float ms[RPB][HH];
    __shared__ __align__(16) float part[4][HH];

    int q = t >> 5;       // neighbor slot 0..3
    int c = t & 31;       // float4 column chunk 0..31
    int lane = t & 63, wv = t >> 6;
    const float4* __restrict__ h4 = (const float4*)h;

    for (int r = 0; r < RPB; ++r) {
        int i = i0 + r;
        // ---- decode mask row into LDS list ----
        unsigned word = mask[(size_t)i * 128 + t];
        int pc = __popc(word);
        int x = pc;
        for (int s = 1; s < 64; s <<= 1) {
            int v = __shfl_up(x, s);
            if (lane >= s) x += v;
        }
        if (lane == 63) wtot[wv] = x;
        __syncthreads();
        int ofs = x - pc + (wv ? wtot[0] : 0);
        int ncnt = wtot[0] + wtot[1];
        unsigned ww = word;
        while (ww) {
            int b = __ffs(ww) - 1; ww &= ww - 1;
            list[ofs++] = (unsigned short)(b * 128 + t);
        }
        hs[r][t] = h[(size_t)i * HH + t];
        __syncthreads();

        // ---- gather ----
        float4 a0 = {0,0,0,0}, a1 = {0,0,0,0}, a2 = {0,0,0,0}, a3 = {0,0,0,0};
        int g = 0;
        for (; g + 16 <= ncnt; g += 16) {
            int j0 = list[g + q];
            int j1 = list[g + 4 + q];
            int j2 = list[g + 8 + q];
            int j3 = list[g + 12 + q];
            float4 v0 = h4[j0 * 32 + c];
            float4 v1 = h4[j1 * 32 + c];
            float4 v2 = h4[j2 * 32 + c];
            float4 v3 = h4[j3 * 32 + c];
            a0.x += v0.x; a0.y += v0.y; a0.z += v0.z; a0.w += v0.w;
            a1.x += v1.x; a1.y += v1.y; a1.z += v1.z; a1.w += v1.w;
            a2.x += v2.x; a2.y += v2.y; a2.z += v2.z; a2.w += v2.w;
            a3.x += v3.x; a3.y += v3.y; a3.z += v3.z; a3.w += v3.w;
        }
        for (; g + 4 <= ncnt; g += 4) {
            int j0 = list[g + q];
            float4 v0 = h4[j0 * 32 + c];
            a0.x += v0.x; a0.y += v0.y; a0.z += v0.z; a0.w += v0.w;
        }
        int rem = ncnt - g;
        if (q < rem) {
            int j0 = list[g + q];
            float4 v0 = h4[j0 * 32 + c];
            a1.x += v0.x; a1.y += v0.y; a1.z += v0.z; a1.w += v0.w;
        }
        float4 tt;
        tt.x = a0.x + a1.x + a2.x + a3.x;
        tt.y = a0.y + a1.y + a2.y + a3.y;
        tt.z = a0.z + a1.z + a2.z + a3.z;
        tt.w = a0.w + a1.w + a2.w + a3.w;
        ((float4*)part[q])[c] = tt;
        __syncthreads();

        float e = part[0][t] + part[1][t] + part[2][t] + part[3][t];
        int ti = sat[i]; ti = min(max(ti, 0), NTYPES - 1);
        float rdeg = 1.f / deg[i];
        ms[r][t] = (S[ti * HH + t] - hs[r][t] + e) * rdeg;
        __syncthreads();   // protect list/wtot/part reuse; ms complete
    }

    // ---- matmul: thread t = output o; W loaded once, reused over RPB rows ----
    const float4* __restrict__ Wl4 = (const float4*)Wl + t * 32;
    const float4* __restrict__ Wr4 = (const float4*)Wr + t * 32;
    float bias = bl[t];
    float acc[RPB];
    #pragma unroll
    for (int r = 0; r < RPB; ++r) acc[r] = bias;
    for (int qq = 0; qq < 32; ++qq) {
        float4 wa = Wl4[qq];
        float4 wb = Wr4[qq];
        #pragma unroll
        for (int r = 0; r < RPB; ++r) {
            float4 mm = ((const float4*)ms[r])[qq];   // LDS broadcast
            float4 hh = ((const float4*)hs[r])[qq];
            acc[r] += mm.x * wa.x + mm.y * wa.y + mm.z * wa.z + mm.w * wa.w
                    + hh.x * wb.x + hh.y * wb.y + hh.z * wb.z + hh.w * wb.w;
        }
    }
    #pragma unroll
    for (int r = 0; r < RPB; ++r)
        hout[(size_t)(i0 + r) * HH + t] = fmaxf(acc[r], 0.f);
}

// ---------------------------------------------------------------------------
// Kernel E: batchnorm stats (sum, sumsq per column)
// ---------------------------------------------------------------------------
__global__ __launch_bounds__(HH) void bn_stats(
    const float* __restrict__ h, float* __restrict__ musum,
    float* __restrict__ varsum)
{
    int k = threadIdx.x;
    int base = blockIdx.x * 128;
    float s = 0.f, s2 = 0.f;
    for (int r = 0; r < 128; ++r) {
        float v = h[(size_t)(base + r) * HH + k];
        s += v; s2 += v * v;
    }
    atomicAdd(&musum[k], s);
    atomicAdd(&varsum[k], s2);
}

// ---------------------------------------------------------------------------
// Kernel F v2: batchnorm apply + head; 16 rows/block, shuffle reductions.
// ---------------------------------------------------------------------------
__global__ __launch_bounds__(HH) void finalize(
    const float* __restrict__ h, const float* __restrict__ musum,
    const float* __restrict__ varsum, const float* __restrict__ gamma,
    const float* __restrict__ beta, const float* __restrict__ Wo,
    const float* __restrict__ bo, float* __restrict__ out_h,
    float* __restrict__ out_o)
{
    int k = threadIdx.x;
    int base = blockIdx.x * 16;
    float mu = musum[k] * (1.f / NN);
    float var = varsum[k] * (1.f / NN) - mu * mu;
    float inv = 1.f / sqrtf(var + BN_EPS);
    float scale = gamma[k] * inv;
    float shift = beta[k] - mu * scale;
    float w0 = Wo[k], w1 = Wo[HH + k], w2 = Wo[2 * HH + k];
    float b0 = bo[0], b1 = bo[1], b2 = bo[2];
    int lane = k & 63, wv = k >> 6;
    __shared__ float red[2][3];
    for (int r = 0; r < 16; ++r) {
        int i = base + r;
        float hb = h[(size_t)i * HH + k] * scale + shift;
        out_h[(size_t)i * HH + k] = hb;
        float p0 = hb * w0, p1 = hb * w1, p2 = hb * w2;
        for (int s = 32; s; s >>= 1) {
            p0 += __shfl_down(p0, s);
            p1 += __shfl_down(p1, s);
            p2 += __shfl_down(p2, s);
        }
        if (lane == 0) { red[wv][0] = p0; red[wv][1] = p1; red[wv][2] = p2; }
        __syncthreads();
        if (k == 0) {
            out_o[(size_t)i * OUTD + 0] = red[0][0] + red[1][0] + b0;
            out_o[(size_t)i * OUTD + 1] = red[0][1] + red[1][1] + b1;
            out_o[(size_t)i * OUTD + 2] = red[0][2] + red[1][2] + b2;
        }
        __syncthreads();
    }
}

// ---------------------------------------------------------------------------
extern "C" void kernel_launch(void* const* d_in, const int* in_sizes, int n_in,
                              void* d_out, int out_size, void* d_ws, size_t ws_size,
                              hipStream_t stream)
{
    (void)in_sizes; (void)n_in; (void)out_size; (void)ws_size;
    const float* x_now = (const float*)d_in[0];
    const int*   sat   = (const int*)d_in[1];
    const float* Wl    = (const float*)d_in[2];
    const float* bl    = (const float*)d_in[3];
    const float* Wr    = (const float*)d_in[4];
    const float* gamma = (const float*)d_in[5];
    const float* beta  = (const float*)d_in[6];
    const float* Wo    = (const float*)d_in[7];
    const float* bo    = (const float*)d_in[8];

    float* ws = (float*)d_ws;
    float* x0 = ws;                          // 524288 floats
    float* h1 = x0 + (size_t)NN * HH;        // 524288
    float* h2 = h1 + (size_t)NN * HH;        // 524288
    float4* fn = (float4*)(h2 + (size_t)NN * HH);      // 4096 float4
    unsigned* mask = (unsigned*)((float*)fn + 4 * NN); // 524288 words
    float* deg = (float*)(mask + (size_t)NN * 128);    // 4096
    int* cnt = (int*)(deg + NN);             // 8 ints
    float* S0 = (float*)(cnt + 8);           // 768
    float* S1 = S0 + NTYPES * HH;            // 768
    float* musum = S1 + NTYPES * HH;         // 128
    float* varsum = musum + HH;              // 128

    size_t zero_bytes = (8 + 2 * NTYPES * HH + 2 * HH) * sizeof(float);
    hipMemsetAsync(cnt, 0, zero_bytes, stream);

    build_x_fn<<<NN, HH, 0, stream>>>(x_now, sat, x0, fn, cnt);
    build_mask<<<NN, HH, 0, stream>>>(fn, sat, cnt, mask, deg);

    type_sums<<<32, HH, 0, stream>>>(x0, sat, S0);
    layer_kernel<<<NN / RPB, HH, 0, stream>>>(x0, mask, deg, S0, sat,
                                              Wl, bl, Wr, h1);
    type_sums<<<32, HH, 0, stream>>>(h1, sat, S1);
    layer_kernel<<<NN / RPB, HH, 0, stream>>>(h1, mask, deg, S1, sat,
                                              Wl + 16384, bl + HH, Wr + 16384, h2);

    bn_stats<<<32, HH, 0, stream>>>(h2, musum, varsum);
    finalize<<<NN / 16, HH, 0, stream>>>(h2, musum, varsum, gamma, beta, Wo, bo,
                                         (float*)d_out, (float*)d_out + (size_t)NN * HH);
}

// Round 3
// 194.761 us; speedup vs baseline: 1.8816x; 1.2448x over previous
//
#include <hip/hip_runtime.h>
#include <hip/hip_bf16.h>
#include <math.h>

#define NN 4096
#define DD 127
#define HH 128
#define OUTD 3
#define NTYPES 6
#define SIM_THRESH 0.9f
#define BN_EPS 1e-5f
#define RPB 4   // rows per block in layer_kernel: amortizes W loads 4x
#define MROW 4  // rows per block in build_mask: amortizes fn reads 4x

// ---------------------------------------------------------------------------
// Kernel H: per-type histogram via wave ballot (no atomic hot-spotting).
// 4 blocks x 256 threads = 16 waves; each wave ballots 64 elems/iter,
// lane 0 does 6 atomicAdds at the end -> 96 global atomics total.
// ---------------------------------------------------------------------------
__global__ __launch_bounds__(256) void type_hist(
    const int* __restrict__ sat, int* __restrict__ cnt)
{
    int gid = blockIdx.x * 256 + threadIdx.x;
    int lane = threadIdx.x & 63;
    int c[NTYPES] = {0, 0, 0, 0, 0, 0};
    for (int i = gid; i < NN; i += 4 * 256) {
        int s = sat[i]; s = min(max(s, 0), NTYPES - 1);
        #pragma unroll
        for (int t = 0; t < NTYPES; ++t)
            c[t] += (int)((__ballot(s == t) >> lane) & 1ull) ? 0 : 0; // placeholder
    }
    // (ballot form below — the loop above is replaced by a simpler exact count)
    // NOTE: simpler correct approach: each lane counts its own elements,
    // then shuffle-reduce per type.
    // Recompute cleanly:
    int cc[NTYPES] = {0, 0, 0, 0, 0, 0};
    for (int i = gid; i < NN; i += 4 * 256) {
        int s = sat[i]; s = min(max(s, 0), NTYPES - 1);
        #pragma unroll
        for (int t = 0; t < NTYPES; ++t) cc[t] += (s == t);
    }
    #pragma unroll
    for (int t = 0; t < NTYPES; ++t) {
        int v = cc[t];
        for (int s = 32; s; s >>= 1) v += __shfl_down(v, s);
        if (lane == 0 && v) atomicAdd(&cnt[t], v);
    }
}

// ---------------------------------------------------------------------------
// Kernel A: build x = concat(x_now[:, :1], x_now) (N x 128) and normalized
// feature fn[i] = normalize([x0,x0,x1,x2]). (histogram moved to type_hist)
// ---------------------------------------------------------------------------
__global__ __launch_bounds__(HH) void build_x_fn(
    const float* __restrict__ x_now, const int* __restrict__ sat,
    float* __restrict__ x, float4* __restrict__ fn)
{
    int i = blockIdx.x;
    int k = threadIdx.x;
    const float* row = x_now + (size_t)i * DD;
    float v = (k == 0) ? row[0] : row[k - 1];
    x[(size_t)i * HH + k] = v;
    if (k == 0) {
        float f0 = row[0], f2 = row[1], f3 = row[2];
        float nrm = sqrtf(2.f * f0 * f0 + f2 * f2 + f3 * f3);
        nrm = fmaxf(nrm, 1e-12f);
        float inv = 1.f / nrm;
        fn[i] = make_float4(f0 * inv, f0 * inv, f2 * inv, f3 * inv);
    }
}

// ---------------------------------------------------------------------------
// Kernel B v2: cross-type cosine adjacency bitmask + degree, MROW rows per
// block — each fn[j]/sat[j] load is reused for MROW rows.
// Bit layout: word w (0..127) of row i, bit b (0..31) <-> j = b*128 + w.
// ---------------------------------------------------------------------------
__global__ __launch_bounds__(HH) void build_mask(
    const float4* __restrict__ fn, const int* __restrict__ sat,
    const int* __restrict__ cnt, unsigned* __restrict__ mask,
    float* __restrict__ deg)
{
    int i0 = blockIdx.x * MROW;
    int w = threadIdx.x;  // 0..127
    float4 fi[MROW];
    int ti[MROW];
    #pragma unroll
    for (int r = 0; r < MROW; ++r) {
        fi[r] = fn[i0 + r];
        int t = sat[i0 + r];
        ti[r] = min(max(t, 0), NTYPES - 1);
    }
    unsigned word[MROW] = {0, 0, 0, 0};
    for (int b = 0; b < 32; ++b) {
        int j = b * 128 + w;
        float4 fj = fn[j];
        int tj = sat[j];
        #pragma unroll
        for (int r = 0; r < MROW; ++r) {
            float dot = fi[r].x * fj.x + fi[r].y * fj.y
                      + fi[r].z * fj.z + fi[r].w * fj.w;
            if (tj != ti[r] && dot > SIM_THRESH) word[r] |= (1u << b);
        }
    }
    int pcs[MROW];
    #pragma unroll
    for (int r = 0; r < MROW; ++r) {
        mask[(size_t)(i0 + r) * 128 + w] = word[r];
        pcs[r] = __popc(word[r]);
    }
    int lane = w & 63, wv = w >> 6;
    for (int s = 32; s; s >>= 1) {
        #pragma unroll
        for (int r = 0; r < MROW; ++r) pcs[r] += __shfl_down(pcs[r], s);
    }
    __shared__ int wt[2][MROW];
    if (lane == 0) {
        #pragma unroll
        for (int r = 0; r < MROW; ++r) wt[wv][r] = pcs[r];
    }
    __syncthreads();
    if (w < MROW) {
        int r = w;
        float d = (float)(cnt[ti[0]] * 0 + cnt[min(max(sat[i0 + r], 0), NTYPES - 1)]
                          - 1 + wt[0][r] + wt[1][r]);
        deg[i0 + r] = fmaxf(d, 1.0f);
    }
}

// ---------------------------------------------------------------------------
// Kernel C: per-type column sums S[t][k] = sum_{i: type(i)=t} h[i][k]
// ---------------------------------------------------------------------------
__global__ __launch_bounds__(HH) void type_sums(
    const float* __restrict__ h, const int* __restrict__ sat,
    float* __restrict__ S)
{
    int k = threadIdx.x;
    int base = blockIdx.x * 128;
    __shared__ float ls[NTYPES][HH];
    for (int t = 0; t < NTYPES; ++t) ls[t][k] = 0.f;
    for (int r = 0; r < 128; ++r) {
        int i = base + r;
        int t = sat[i]; t = min(max(t, 0), NTYPES - 1);
        ls[t][k] += h[(size_t)i * HH + k];
    }
    for (int t = 0; t < NTYPES; ++t) atomicAdd(&S[t * HH + k], ls[t][k]);
}

// ---------------------------------------------------------------------------
// Kernel D v2: RPB rows per block.
// Per row: decode bitmask -> LDS CSR list (wave shfl scan); gather as
// 4 neighbors x 32 float4 chunks with 4 independent accumulators; LDS
// reduce across neighbor slots. Then one matmul phase with W float4 loaded
// once per block, reused across RPB rows via LDS broadcast of ms/hs.
// ---------------------------------------------------------------------------
__global__ __launch_bounds__(HH) void layer_kernel(
    const float* __restrict__ h, const unsigned* __restrict__ mask,
    const float* __restrict__ deg, const float* __restrict__ S,
    const int* __restrict__ sat,
    const float* __restrict__ Wl, const float* __restrict__ bl,
    const float* __restrict__ Wr, float* __restrict__ hout)
{
    int t = threadIdx.x;
    int i0 = blockIdx.x * RPB;
    __shared__ unsigned short list[NN];                 // 8 KB CSR scratch
    __shared__ int wtot[2];
    __shared__ __align__(16) float hs[RPB][HH];
    __shared__ __align__(16) float ms[RPB][HH];
    __shared__ __align__(16) float part[4][HH];

    int q = t >> 5;       // neighbor slot 0..3
    int c = t & 31;       // float4 column chunk 0..31
    int lane = t & 63, wv = t >> 6;
    const float4* __restrict__ h4 = (const float4*)h;

    for (int r = 0; r < RPB; ++r) {
        int i = i0 + r;
        // ---- decode mask row into LDS list ----
        unsigned word = mask[(size_t)i * 128 + t];
        int pc = __popc(word);
        int x = pc;
        for (int s = 1; s < 64; s <<= 1) {
            int v = __shfl_up(x, s);
            if (lane >= s) x += v;
        }
        if (lane == 63) wtot[wv] = x;
        __syncthreads();
        int ofs = x - pc + (wv ? wtot[0] : 0);
        int ncnt = wtot[0] + wtot[1];
        unsigned ww = word;
        while (ww) {
            int b = __ffs(ww) - 1; ww &= ww - 1;
            list[ofs++] = (unsigned short)(b * 128 + t);
        }
        hs[r][t] = h[(size_t)i * HH + t];
        __syncthreads();

        // ---- gather ----
        float4 a0 = {0,0,0,0}, a1 = {0,0,0,0}, a2 = {0,0,0,0}, a3 = {0,0,0,0};
        int g = 0;
        for (; g + 16 <= ncnt; g += 16) {
            int j0 = list[g + q];
            int j1 = list[g + 4 + q];
            int j2 = list[g + 8 + q];
            int j3 = list[g + 12 + q];
            float4 v0 = h4[j0 * 32 + c];
            float4 v1 = h4[j1 * 32 + c];
            float4 v2 = h4[j2 * 32 + c];
            float4 v3 = h4[j3 * 32 + c];
            a0.x += v0.x; a0.y += v0.y; a0.z += v0.z; a0.w += v0.w;
            a1.x += v1.x; a1.y += v1.y; a1.z += v1.z; a1.w += v1.w;
            a2.x += v2.x; a2.y += v2.y; a2.z += v2.z; a2.w += v2.w;
            a3.x += v3.x; a3.y += v3.y; a3.z += v3.z; a3.w += v3.w;
        }
        for (; g + 4 <= ncnt; g += 4) {
            int j0 = list[g + q];
            float4 v0 = h4[j0 * 32 + c];
            a0.x += v0.x; a0.y += v0.y; a0.z += v0.z; a0.w += v0.w;
        }
        int rem = ncnt - g;
        if (q < rem) {
            int j0 = list[g + q];
            float4 v0 = h4[j0 * 32 + c];
            a1.x += v0.x; a1.y += v0.y; a1.z += v0.z; a1.w += v0.w;
        }
        float4 tt;
        tt.x = a0.x + a1.x + a2.x + a3.x;
        tt.y = a0.y + a1.y + a2.y + a3.y;
        tt.z = a0.z + a1.z + a2.z + a3.z;
        tt.w = a0.w + a1.w + a2.w + a3.w;
        ((float4*)part[q])[c] = tt;
        __syncthreads();

        float e = part[0][t] + part[1][t] + part[2][t] + part[3][t];
        int ti = sat[i]; ti = min(max(ti, 0), NTYPES - 1);
        float rdeg = 1.f / deg[i];
        ms[r][t] = (S[ti * HH + t] - hs[r][t] + e) * rdeg;
        __syncthreads();   // protect list/wtot/part reuse; ms complete
    }

    // ---- matmul: thread t = output o; W loaded once, reused over RPB rows ----
    const float4* __restrict__ Wl4 = (const float4*)Wl + t * 32;
    const float4* __restrict__ Wr4 = (const float4*)Wr + t * 32;
    float bias = bl[t];
    float acc[RPB];
    #pragma unroll
    for (int r = 0; r < RPB; ++r) acc[r] = bias;
    for (int qq = 0; qq < 32; ++qq) {
        float4 wa = Wl4[qq];
        float4 wb = Wr4[qq];
        #pragma unroll
        for (int r = 0; r < RPB; ++r) {
            float4 mm = ((const float4*)ms[r])[qq];   // LDS broadcast
            float4 hh = ((const float4*)hs[r])[qq];
            acc[r] += mm.x * wa.x + mm.y * wa.y + mm.z * wa.z + mm.w * wa.w
                    + hh.x * wb.x + hh.y * wb.y + hh.z * wb.z + hh.w * wb.w;
        }
    }
    #pragma unroll
    for (int r = 0; r < RPB; ++r)
        hout[(size_t)(i0 + r) * HH + t] = fmaxf(acc[r], 0.f);
}

// ---------------------------------------------------------------------------
// Kernel E: batchnorm stats (sum, sumsq per column)
// ---------------------------------------------------------------------------
__global__ __launch_bounds__(HH) void bn_stats(
    const float* __restrict__ h, float* __restrict__ musum,
    float* __restrict__ varsum)
{
    int k = threadIdx.x;
    int base = blockIdx.x * 128;
    float s = 0.f, s2 = 0.f;
    for (int r = 0; r < 128; ++r) {
        float v = h[(size_t)(base + r) * HH + k];
        s += v; s2 += v * v;
    }
    atomicAdd(&musum[k], s);
    atomicAdd(&varsum[k], s2);
}

// ---------------------------------------------------------------------------
// Kernel F v2: batchnorm apply + head; 16 rows/block, shuffle reductions.
// ---------------------------------------------------------------------------
__global__ __launch_bounds__(HH) void finalize(
    const float* __restrict__ h, const float* __restrict__ musum,
    const float* __restrict__ varsum, const float* __restrict__ gamma,
    const float* __restrict__ beta, const float* __restrict__ Wo,
    const float* __restrict__ bo, float* __restrict__ out_h,
    float* __restrict__ out_o)
{
    int k = threadIdx.x;
    int base = blockIdx.x * 16;
    float mu = musum[k] * (1.f / NN);
    float var = varsum[k] * (1.f / NN) - mu * mu;
    float inv = 1.f / sqrtf(var + BN_EPS);
    float scale = gamma[k] * inv;
    float shift = beta[k] - mu * scale;
    float w0 = Wo[k], w1 = Wo[HH + k], w2 = Wo[2 * HH + k];
    float b0 = bo[0], b1 = bo[1], b2 = bo[2];
    int lane = k & 63, wv = k >> 6;
    __shared__ float red[2][3];
    for (int r = 0; r < 16; ++r) {
        int i = base + r;
        float hb = h[(size_t)i * HH + k] * scale + shift;
        out_h[(size_t)i * HH + k] = hb;
        float p0 = hb * w0, p1 = hb * w1, p2 = hb * w2;
        for (int s = 32; s; s >>= 1) {
            p0 += __shfl_down(p0, s);
            p1 += __shfl_down(p1, s);
            p2 += __shfl_down(p2, s);
        }
        if (lane == 0) { red[wv][0] = p0; red[wv][1] = p1; red[wv][2] = p2; }
        __syncthreads();
        if (k == 0) {
            out_o[(size_t)i * OUTD + 0] = red[0][0] + red[1][0] + b0;
            out_o[(size_t)i * OUTD + 1] = red[0][1] + red[1][1] + b1;
            out_o[(size_t)i * OUTD + 2] = red[0][2] + red[1][2] + b2;
        }
        __syncthreads();
    }
}

// ---------------------------------------------------------------------------
extern "C" void kernel_launch(void* const* d_in, const int* in_sizes, int n_in,
                              void* d_out, int out_size, void* d_ws, size_t ws_size,
                              hipStream_t stream)
{
    (void)in_sizes; (void)n_in; (void)out_size; (void)ws_size;
    const float* x_now = (const float*)d_in[0];
    const int*   sat   = (const int*)d_in[1];
    const float* Wl    = (const float*)d_in[2];
    const float* bl    = (const float*)d_in[3];
    const float* Wr    = (const float*)d_in[4];
    const float* gamma = (const float*)d_in[5];
    const float* beta  = (const float*)d_in[6];
    const float* Wo    = (const float*)d_in[7];
    const float* bo    = (const float*)d_in[8];

    float* ws = (float*)d_ws;
    float* x0 = ws;                          // 524288 floats
    float* h1 = x0 + (size_t)NN * HH;        // 524288
    float* h2 = h1 + (size_t)NN * HH;        // 524288
    float4* fn = (float4*)(h2 + (size_t)NN * HH);      // 4096 float4
    unsigned* mask = (unsigned*)((float*)fn + 4 * NN); // 524288 words
    float* deg = (float*)(mask + (size_t)NN * 128);    // 4096
    int* cnt = (int*)(deg + NN);             // 8 ints
    float* S0 = (float*)(cnt + 8);           // 768
    float* S1 = S0 + NTYPES * HH;            // 768
    float* musum = S1 + NTYPES * HH;         // 128
    float* varsum = musum + HH;              // 128

    size_t zero_bytes = (8 + 2 * NTYPES * HH + 2 * HH) * sizeof(float);
    hipMemsetAsync(cnt, 0, zero_bytes, stream);

    type_hist<<<4, 256, 0, stream>>>(sat, cnt);
    build_x_fn<<<NN, HH, 0, stream>>>(x_now, sat, x0, fn);
    build_mask<<<NN / MROW, HH, 0, stream>>>(fn, sat, cnt, mask, deg);

    type_sums<<<32, HH, 0, stream>>>(x0, sat, S0);
    layer_kernel<<<NN / RPB, HH, 0, stream>>>(x0, mask, deg, S0, sat,
                                              Wl, bl, Wr, h1);
    type_sums<<<32, HH, 0, stream>>>(h1, sat, S1);
    layer_kernel<<<NN / RPB, HH, 0, stream>>>(h1, mask, deg, S1, sat,
                                              Wl + 16384, bl + HH, Wr + 16384, h2);

    bn_stats<<<32, HH, 0, stream>>>(h2, musum, varsum);
    finalize<<<NN / 16, HH, 0, stream>>>(h2, musum, varsum, gamma, beta, Wo, bo,
                                         (float*)d_out, (float*)d_out + (size_t)NN * HH);
}